// Round 5
// baseline (146.322 us; speedup 1.0000x reference)
//
#include <hip/hip_runtime.h>
#include <hip/hip_bf16.h>

using sh4     = __attribute__((ext_vector_type(4))) short;
using short8  = __attribute__((ext_vector_type(8))) short;
using floatx4 = __attribute__((ext_vector_type(4))) float;

// async global->LDS copy, 16B per lane: LDS dest = wave-uniform base + lane*16,
// global src = per-lane address. Matches the frag-linear prepack layout exactly.
__device__ __forceinline__ void gl_lds16(const __hip_bfloat16* g, __hip_bfloat16* l) {
    __builtin_amdgcn_global_load_lds(
        (const __attribute__((address_space(1))) void*)g,
        (__attribute__((address_space(3))) void*)l, 16, 0, 0);
}

// ---------------------------------------------------------------------------
// prepack: weights fp32 -> bf16 in MFMA-B-fragment-tiled layout.
// Fragment (nblk, kstep) occupies 64 lanes x 8 elems contiguous; lane l holds
// B[n = nblk*16 + (l&15)][k = kstep*32 + (l>>4)*8 .. +7]  (verified B-frag
// mapping: row=lane&15, k=quad*8+j). One frag = 1 KiB, lane l at bytes
// [l*16, l*16+16) -- byte-exact for global_load_lds AND for conflict-free
// contiguous ds_read_b128 consumption.
//  wsb_t: from w_sample [256 s][1024 k]  -> 16 nblk x 32 kstep   (262144 elems)
//  wib_t: from w_init  [1024 k'][256 s]  -> 64 nblk x  8 kstep   (262144 elems)
// ---------------------------------------------------------------------------
__global__ __launch_bounds__(256) void prepack_kernel(const float* __restrict__ w_sample,
                                                      const float* __restrict__ w_init,
                                                      __hip_bfloat16* __restrict__ wsb_t,
                                                      __hip_bfloat16* __restrict__ wib_t) {
    const int tg   = blockIdx.x * 256 + threadIdx.x;   // 0..65535
    const int lane = tg & 63;
    const int l16  = lane & 15, quad = lane >> 4;
    const float* src;
    __hip_bfloat16* dst;
    if (tg < 32768) {
        const int chunk = tg >> 6;                     // 0..511: nblk=chunk>>5, kstep=chunk&31
        const int n = (chunk >> 5) * 16 + l16;
        const int k = (chunk & 31) * 32 + quad * 8;
        src = w_sample + (size_t)n * 1024 + k;
        dst = wsb_t + (size_t)tg * 8;
    } else {
        const int t2 = tg - 32768;
        const int chunk = t2 >> 6;                     // 0..511: nblk=chunk>>3, kstep=chunk&7
        const int n = (chunk >> 3) * 16 + l16;
        const int k = (chunk & 7) * 32 + quad * 8;
        src = w_init + (size_t)n * 256 + k;
        dst = wib_t + (size_t)t2 * 8;
    }
    floatx4 v0 = *(const floatx4*)(src);
    floatx4 v1 = *(const floatx4*)(src + 4);
    union { short8 s; __hip_bfloat16 h[8]; } u;
#pragma unroll
    for (int i = 0; i < 4; ++i) {
        u.h[i]     = __float2bfloat16(v0[i]);
        u.h[4 + i] = __float2bfloat16(v1[i]);
    }
    *(short8*)dst = u.s;
}

// ---------------------------------------------------------------------------
// fused v5 = round-0 structure (256 thr / 4 waves, grid 512 = 2 blocks/CU,
// wave tile 32x64) with ONE change: phase-1 B-fragments now go through an
// LDS double-buffer filled by global_load_lds (m97 staging pattern,
// Common-mistake #1 fix) instead of register-direct L2 loads.
//  - BK=32, 32 iters. Per iter each wave issues 4 async frag-DMAs for it+1
//    (wave-private LDS slots -> no extra sync; the existing barrier's
//    vmcnt(0) drain completes them after a full iteration in flight),
//    and consumes iter-it frags from LDS via contiguous conflict-free
//    ds_read_b128 (lane l reads bytes [l*16,l*16+16) of its frag).
//  - L2 latency leaves the per-iteration critical path entirely.
//  - As [32][40] fp-? bf16 ping-pong (4 KB x-chunk = row it of all 32
//    patches, contiguous; 1 floatx4 load + cvt + 8B ds_write per thread).
//  - LDS: As 5 KB + Bs 32 KB + Ms 16.9 KB = 54.8 KB -> 2 blocks/CU.
// Phase 2 identical to the proven round-0 form (barrier-free, B register-
// direct from L2 -- it has no per-iter barrier so latency pipelines there).
// Verified layouts: A/B frag row=lane&15, k=quad*8+j; C/D col=lane&15,
// row=quad*4+reg.
// ---------------------------------------------------------------------------
__global__ __launch_bounds__(256, 2) void fused_kernel(const float* __restrict__ x,
                                                       const __hip_bfloat16* __restrict__ wsb_t,
                                                       const __hip_bfloat16* __restrict__ wib_t,
                                                       float* __restrict__ Y) {
    __shared__ __hip_bfloat16 As[2][32 * 40];  // ping-pong A tile [32][40], BK=32
    __shared__ __hip_bfloat16 Bs[2][16 * 512]; // ping-pong B frags: 16 x 1KB per half
    __shared__ __hip_bfloat16 Ms[32 * 264];    // meas tile, row stride 264

    const int tid  = threadIdx.x;
    const int wave = tid >> 6, lane = tid & 63;
    const int quad = lane >> 4, l16 = lane & 15;
    const int blk  = blockIdx.x;               // blk = b*32 + nh

    // x chunk for iter it = slab row it (4 KB contiguous): thread t -> floatx4
    // at +t*4; maps to As[m = t>>3][c = (t&7)*4 ..+3]
    const float* srcX = x + (size_t)blk * 32768 + tid * 4;
    const int sidx = (tid >> 3) * 40 + (tid & 7) * 4;

    // B-frag global base (same frag indexing as round 0: frag (wave*4+j, ks)
    // at elem (wave*65536 + (j*32+ks)*512); per-lane src = +lane*8)
    const __hip_bfloat16* baseW1 = wsb_t + (size_t)wave * 65536 + lane * 8;
    const __hip_bfloat16* baseW2 = wib_t + (size_t)wave * 16384 + lane * 8;
    // wave-private LDS frag slots: wave*4+j -> elem (wave*4+j)*512
    __hip_bfloat16* lB0 = &Bs[0][wave * 2048];
    __hip_bfloat16* lB1 = &Bs[1][wave * 2048];

    floatx4 acc[2][4];
#pragma unroll
    for (int i = 0; i < 2; ++i)
#pragma unroll
        for (int j = 0; j < 4; ++j) acc[i][j] = {0.f, 0.f, 0.f, 0.f};

    // ---------------- phase 1 (32 iters, BK=32) ----------------
    floatx4 v = *(const floatx4*)(srcX);
    srcX += 1024;
#pragma unroll
    for (int j = 0; j < 4; ++j)                 // B(0) prologue DMA
        gl_lds16(baseW1 + (size_t)(j * 32) * 512, lB0 + j * 512);

    for (int it = 0; it < 32; ++it) {
        union { sh4 s; __hip_bfloat16 h[4]; } u;
#pragma unroll
        for (int q = 0; q < 4; ++q) u.h[q] = __float2bfloat16(v[q]);
        *(sh4*)&As[it & 1][sidx] = u.s;
        __syncthreads();                        // As(it) visible; B(it) DMA done
        if (it < 31) {                          // prefetch it+1: x chunk + B DMA
            v = *(const floatx4*)(srcX);
            srcX += 1024;
            __hip_bfloat16* lB = (it & 1) ? lB0 : lB1;   // slot (it+1)&1
#pragma unroll
            for (int j = 0; j < 4; ++j)
                gl_lds16(baseW1 + (size_t)(j * 32 + it + 1) * 512, lB + j * 512);
        }
        const __hip_bfloat16* Ap = As[it & 1];
        const __hip_bfloat16* Bp = ((it & 1) ? lB1 : lB0) + lane * 8;
        short8 af[2], bfr[4];
#pragma unroll
        for (int i = 0; i < 2; ++i)
            af[i] = *(const short8*)&Ap[(i * 16 + l16) * 40 + quad * 8];
#pragma unroll
        for (int j = 0; j < 4; ++j)
            bfr[j] = *(const short8*)(Bp + j * 512);
#pragma unroll
        for (int i = 0; i < 2; ++i)
#pragma unroll
            for (int j = 0; j < 4; ++j)
                acc[i][j] = __builtin_amdgcn_mfma_f32_16x16x32_bf16(af[i], bfr[j], acc[i][j], 0, 0, 0);
    }

    // meas (C-layout) -> Ms row-major [m][s]; wave strip = cols [64w, 64w+64)
#pragma unroll
    for (int i = 0; i < 2; ++i)
#pragma unroll
        for (int r = 0; r < 4; ++r) {
            const int row = i * 16 + quad * 4 + r;
#pragma unroll
            for (int j = 0; j < 4; ++j)
                Ms[row * 264 + wave * 64 + j * 16 + l16] = __float2bfloat16(acc[i][j][r]);
        }
    __syncthreads();

    // ---------------- phase 2 (barrier-free) ----------------
    float* ybase = Y + (size_t)blk * 32768;
#pragma unroll 1
    for (int c = 0; c < 4; ++c) {
        floatx4 a2[2][4];
#pragma unroll
        for (int i = 0; i < 2; ++i)
#pragma unroll
            for (int j = 0; j < 4; ++j) a2[i][j] = {0.f, 0.f, 0.f, 0.f};
        const __hip_bfloat16* w2 = baseW2 + (size_t)c * 65536;
#pragma unroll
        for (int ks = 0; ks < 8; ++ks) {
            short8 af[2], bfr[4];
#pragma unroll
            for (int i = 0; i < 2; ++i)
                af[i] = *(const short8*)&Ms[(i * 16 + l16) * 264 + ks * 32 + quad * 8];
#pragma unroll
            for (int j = 0; j < 4; ++j)
                bfr[j] = *(const short8*)(w2 + (size_t)j * 4096 + ks * 512);
#pragma unroll
            for (int i = 0; i < 2; ++i)
#pragma unroll
                for (int j = 0; j < 4; ++j)
                    a2[i][j] = __builtin_amdgcn_mfma_f32_16x16x32_bf16(af[i], bfr[j], a2[i][j], 0, 0, 0);
        }
        // fold epilogue: m = patch; col = c*256 + wave*64 + j*16 + l16 -> (kh,kw)
#pragma unroll
        for (int i = 0; i < 2; ++i)
#pragma unroll
            for (int r = 0; r < 4; ++r) {
                const int m = i * 16 + quad * 4 + r;
#pragma unroll
                for (int j = 0; j < 4; ++j) {
                    const int col = c * 256 + wave * 64 + j * 16 + l16;
                    const int kh = col >> 5, kw = col & 31;
                    ybase[kh * 1024 + m * 32 + kw] = a2[i][j][r];
                }
            }
    }
}

// ---------------------------------------------------------------------------
// Workspace: wsb_t bf16 [262144] @ 0 (524288 B); wib_t bf16 [262144]
// @ 524288 (524288 B). Total 1 MB.
// ---------------------------------------------------------------------------
extern "C" void kernel_launch(void* const* d_in, const int* in_sizes, int n_in,
                              void* d_out, int out_size, void* d_ws, size_t ws_size,
                              hipStream_t stream) {
    const float* x        = (const float*)d_in[0];
    const float* w_sample = (const float*)d_in[1];
    const float* w_init   = (const float*)d_in[2];
    float* y = (float*)d_out;
    char* ws = (char*)d_ws;

    __hip_bfloat16* wsb_t = (__hip_bfloat16*)(ws);
    __hip_bfloat16* wib_t = (__hip_bfloat16*)(ws + (size_t)524288);

    prepack_kernel<<<256, 256, 0, stream>>>(w_sample, w_init, wsb_t, wib_t);
    fused_kernel<<<512, 256, 0, stream>>>(x, wsb_t, wib_t, y);
}

// Round 7
// 141.340 us; speedup vs baseline: 1.0353x; 1.0353x over previous
//
#include <hip/hip_runtime.h>
#include <hip/hip_bf16.h>

using short8  = __attribute__((ext_vector_type(8))) short;
using floatx4 = __attribute__((ext_vector_type(4))) float;

// ---------------------------------------------------------------------------
// prepack: weights fp32 -> bf16 in MFMA-B-fragment-tiled layout (unchanged).
// Fragment (nblk, kstep) = 64 lanes x 8 elems contiguous (1 KiB); lane l holds
// B[n = nblk*16 + (l&15)][k = kstep*32 + (l>>4)*8 .. +7].
//  wsb_t: from w_sample [256 s][1024 k]  -> frag idx = nblk*32 + kstep  (16x32)
//  wib_t: from w_init  [1024 k'][256 s]  -> frag idx = nblk*8  + kstep  (64x8)
// ---------------------------------------------------------------------------
__global__ __launch_bounds__(256) void prepack_kernel(const float* __restrict__ w_sample,
                                                      const float* __restrict__ w_init,
                                                      __hip_bfloat16* __restrict__ wsb_t,
                                                      __hip_bfloat16* __restrict__ wib_t) {
    const int tg   = blockIdx.x * 256 + threadIdx.x;   // 0..65535
    const int lane = tg & 63;
    const int l16  = lane & 15, quad = lane >> 4;
    const float* src;
    __hip_bfloat16* dst;
    if (tg < 32768) {
        const int chunk = tg >> 6;                     // 0..511: nblk=chunk>>5, kstep=chunk&31
        const int n = (chunk >> 5) * 16 + l16;
        const int k = (chunk & 31) * 32 + quad * 8;
        src = w_sample + (size_t)n * 1024 + k;
        dst = wsb_t + (size_t)tg * 8;
    } else {
        const int t2 = tg - 32768;
        const int chunk = t2 >> 6;                     // 0..511: nblk=chunk>>3, kstep=chunk&7
        const int n = (chunk >> 3) * 16 + l16;
        const int k = (chunk & 7) * 32 + quad * 8;
        src = w_init + (size_t)n * 256 + k;
        dst = wib_t + (size_t)t2 * 8;
    }
    floatx4 v0 = *(const floatx4*)(src);
    floatx4 v1 = *(const floatx4*)(src + 4);
    union { short8 s; __hip_bfloat16 h[8]; } u;
#pragma unroll
    for (int i = 0; i < 4; ++i) {
        u.h[i]     = __float2bfloat16(v0[i]);
        u.h[4 + i] = __float2bfloat16(v1[i]);
    }
    *(short8*)dst = u.s;
}

// ---------------------------------------------------------------------------
// phase1: meas[slab][32 m][256 s] = patch[32x1024] @ Ws^T, barrier-FREE K-loop.
//  - grid 512 (slab = b*32+nh), 512 thr = 8 waves (2 blocks/CU, LDS-capped).
//  - stage ENTIRE x slab as bf16 into 64 KB LDS once (ONE barrier), then
//    stream 32 K-steps of {2 ds_read_b128 A, 2 L2 B-frag loads, 8 MFMA}
//    with NO barriers: compiler vmcnt-pipelines across the whole loop.
//  - As swizzle (FIXED from r6: XOR applied to the FULLY-FORMED byte address
//    on BOTH sides -- same involution, bijective, rule-21 compliant):
//      byte = linear ^ ((row&7)<<4)
//    Read: 16 same-column rows -> 8 slots x 2 = conflict-free floor.
//  - meas (bf16, round-0 rounding) parked in Y's own slab head (16 KB of the
//    128 KB phase2 will overwrite) -> zero extra workspace.
// Wave tile 32x32: wave w owns s in [32w,32w+32), nblk {2w,2w+1}; acc[2][2].
// Verified layouts: A/B frag row=lane&15, k=quad*8+j; C/D col=lane&15,
// row=quad*4+reg.
// ---------------------------------------------------------------------------
__global__ __launch_bounds__(512, 4) void phase1_kernel(const float* __restrict__ x,
                                                        const __hip_bfloat16* __restrict__ wsb_t,
                                                        float* __restrict__ Y) {
    __shared__ __hip_bfloat16 As[32 * 1024];   // 64 KB, XOR-swizzled
    const int tid  = threadIdx.x;
    const int wave = tid >> 6, lane = tid & 63;
    const int quad = lane >> 4, l16 = lane & 15;
    const int slab = blockIdx.x;

    // ---- stage: thread t -> 64 consecutive floats = image row rl = t>>4,
    //      cols (t&15)*64..+64 = patches m0=(t&15)*2, m0+1, kw 0..31 each.
    //      As element (m, k=rl*32+kw) at byte (m*2048 + rl*64 + kw*2) ^ X(m).
    {
        const float* src = x + (size_t)slab * 32768 + tid * 64;
        const int rl = tid >> 4;
        const int m0 = (tid & 15) * 2;
#pragma unroll
        for (int seg = 0; seg < 2; ++seg) {
            const float* s = src + seg * 32;
            const int m   = m0 + seg;
            const int lin = m * 2048 + rl * 64;        // byte addr of kw=0
            const int xm  = (m & 7) << 4;
#pragma unroll
            for (int i = 0; i < 4; ++i) {
                floatx4 a = *(const floatx4*)(s + i * 8);
                floatx4 b = *(const floatx4*)(s + i * 8 + 4);
                union { short8 v; __hip_bfloat16 h[8]; } u;
#pragma unroll
                for (int q = 0; q < 4; ++q) {
                    u.h[q]     = __float2bfloat16(a[q]);
                    u.h[4 + q] = __float2bfloat16(b[q]);
                }
                *(short8*)((char*)As + ((lin + i * 16) ^ xm)) = u.v;
            }
        }
    }
    __syncthreads();

    // ---- barrier-free K stream
    const __hip_bfloat16* bw = wsb_t + (size_t)wave * 32768 + (size_t)lane * 8;
    floatx4 acc[2][2];
#pragma unroll
    for (int i = 0; i < 2; ++i)
#pragma unroll
        for (int j = 0; j < 2; ++j) acc[i][j] = {0.f, 0.f, 0.f, 0.f};

#pragma unroll 8
    for (int ks = 0; ks < 32; ++ks) {
        short8 af[2], bfr[2];
#pragma unroll
        for (int i = 0; i < 2; ++i) {
            const int row  = i * 16 + l16;
            const int boff = (row * 2048 + ks * 64 + quad * 16) ^ ((row & 7) << 4);
            af[i] = *(const short8*)((const char*)As + boff);
        }
#pragma unroll
        for (int j = 0; j < 2; ++j)
            bfr[j] = *(const short8*)(bw + (size_t)j * 16384 + (size_t)ks * 512);
#pragma unroll
        for (int i = 0; i < 2; ++i)
#pragma unroll
            for (int j = 0; j < 2; ++j)
                acc[i][j] = __builtin_amdgcn_mfma_f32_16x16x32_bf16(af[i], bfr[j], acc[i][j], 0, 0, 0);
    }

    // ---- meas (bf16) -> Y-head scratch [slab*32768 .. +4096 floats)
    __hip_bfloat16* mb = (__hip_bfloat16*)(Y + (size_t)slab * 32768);
#pragma unroll
    for (int i = 0; i < 2; ++i)
#pragma unroll
        for (int j = 0; j < 2; ++j)
#pragma unroll
            for (int r = 0; r < 4; ++r) {
                const int m = i * 16 + quad * 4 + r;
                const int s = wave * 32 + j * 16 + l16;
                mb[m * 256 + s] = __float2bfloat16(acc[i][j][r]);
            }
}

// ---------------------------------------------------------------------------
// phase2: rec[slab][32 m][1024 n] = meas @ Wi^T, folded into Y. Barrier-free
// K-loop. grid 512, 512 thr = 8 waves; wave owns 128 cols as 2 chunks of 64
// (acc[2][4], round-0-proven register shape). Stage meas 16 KB (raw bf16
// bits from Y-head) -> Ms (stride 264), ONE barrier, stream. All Y writes
// are after the barrier; meas only read before it -> overwrite-safe.
// ---------------------------------------------------------------------------
__global__ __launch_bounds__(512, 4) void phase2_kernel(const __hip_bfloat16* __restrict__ wib_t,
                                                        float* __restrict__ Y) {
    __shared__ __hip_bfloat16 Ms[32 * 264];
    const int tid  = threadIdx.x;
    const int wave = tid >> 6, lane = tid & 63;
    const int quad = lane >> 4, l16 = lane & 15;
    const int slab = blockIdx.x;

    // ---- stage meas: thread t -> 16 bf16 (row t>>4, cols (t&15)*16..+16)
    {
        const floatx4* src = (const floatx4*)(Y + (size_t)slab * 32768) + tid * 2;
        union { floatx4 f; short8 s; } ua, ub;
        ua.f = src[0]; ub.f = src[1];
        __hip_bfloat16* d = &Ms[(tid >> 4) * 264 + (tid & 15) * 16];
        *(short8*)(d)     = ua.s;
        *(short8*)(d + 8) = ub.s;
    }
    __syncthreads();

    // ---- barrier-free K stream: wave owns nblk' [8w, 8w+8)
    const __hip_bfloat16* bw = wib_t + (size_t)wave * 32768 + (size_t)lane * 8;
    float* yb = Y + (size_t)slab * 32768;
#pragma unroll 1
    for (int c = 0; c < 2; ++c) {
        floatx4 a2[2][4];
#pragma unroll
        for (int i = 0; i < 2; ++i)
#pragma unroll
            for (int j = 0; j < 4; ++j) a2[i][j] = {0.f, 0.f, 0.f, 0.f};
        const __hip_bfloat16* w2 = bw + (size_t)c * 16384;     // (c*4)*4096
#pragma unroll
        for (int ks = 0; ks < 8; ++ks) {
            short8 af[2], bfr[4];
#pragma unroll
            for (int i = 0; i < 2; ++i)
                af[i] = *(const short8*)&Ms[(i * 16 + l16) * 264 + ks * 32 + quad * 8];
#pragma unroll
            for (int j = 0; j < 4; ++j)
                bfr[j] = *(const short8*)(w2 + (size_t)j * 4096 + (size_t)ks * 512);
#pragma unroll
            for (int i = 0; i < 2; ++i)
#pragma unroll
                for (int j = 0; j < 4; ++j)
                    a2[i][j] = __builtin_amdgcn_mfma_f32_16x16x32_bf16(af[i], bfr[j], a2[i][j], 0, 0, 0);
        }
        // fold epilogue: col = wave*128 + c*64 + j*16 + l16 -> (kh, kw)
#pragma unroll
        for (int i = 0; i < 2; ++i)
#pragma unroll
            for (int r = 0; r < 4; ++r) {
                const int m = i * 16 + quad * 4 + r;
#pragma unroll
                for (int j = 0; j < 4; ++j) {
                    const int col = wave * 128 + c * 64 + j * 16 + l16;
                    const int kh = col >> 5, kw = col & 31;
                    yb[kh * 1024 + m * 32 + kw] = a2[i][j][r];
                }
            }
    }
}

// ---------------------------------------------------------------------------
// Workspace: wsb_t bf16 [262144] @ 0; wib_t bf16 [262144] @ 524288. 1 MB.
// meas scratch lives inside Y (overwritten by phase2). 3 dispatches.
// ---------------------------------------------------------------------------
extern "C" void kernel_launch(void* const* d_in, const int* in_sizes, int n_in,
                              void* d_out, int out_size, void* d_ws, size_t ws_size,
                              hipStream_t stream) {
    const float* x        = (const float*)d_in[0];
    const float* w_sample = (const float*)d_in[1];
    const float* w_init   = (const float*)d_in[2];
    float* y = (float*)d_out;
    char* ws = (char*)d_ws;

    __hip_bfloat16* wsb_t = (__hip_bfloat16*)(ws);
    __hip_bfloat16* wib_t = (__hip_bfloat16*)(ws + (size_t)524288);

    prepack_kernel<<<256, 256, 0, stream>>>(w_sample, w_init, wsb_t, wib_t);
    phase1_kernel<<<512, 512, 0, stream>>>(x, wsb_t, y);
    phase2_kernel<<<512, 512, 0, stream>>>(wib_t, y);
}